// Round 1
// baseline (2995.647 us; speedup 1.0000x reference)
//
#include <hip/hip_runtime.h>

// Problem constants (reference: N=8192, D=128, NK=2, ORDER=2, EMB=64, IN_DIM=896)
#define NN 8192
#define DD 128
#define EMB 64
#define INDIM 896

// ---------------------------------------------------------------------------
// Algebra: with cnt[c] = #{i : n_id[i] == c},
//   xdiff        = x - tau * L @ x                      [N,128]
//   xz[c,d]      = cnt[c] * xdiff[c,d]                  [N,128]
//   Y1[k,r,d]    = (K[k] @ xz)[r,d]                     [2,N,128]
//   z2[c,k1*128+d] = cnt[c] * Y1[k1,c,d]                [N,256]
//   Y2[k,r,f]    = (K[k] @ z2)[r,f]                     [2,N,256]
//   feat(r)      = [xdiff[r], Y1[0,r], Y1[1,r], Y2[0,r], Y2[1,r]]   (896)
//   E[r,e]       = tanh(feat(r) . W[:,e] + b[e])        [N,64]
//   out[j]       = E[n_id[j]]
// ---------------------------------------------------------------------------

__global__ void zero_f(float* p, int n) {
    int i = blockIdx.x * blockDim.x + threadIdx.x;
    if (i < n) p[i] = 0.0f;
}

__global__ void hist_k(const int* __restrict__ n_id, float* __restrict__ cnt) {
    int i = blockIdx.x * blockDim.x + threadIdx.x;
    if (i < NN) atomicAdd(&cnt[n_id[i]], 1.0f);
}

__global__ void scale_xz(const float* __restrict__ xdiff,
                         const float* __restrict__ cnt,
                         float* __restrict__ xz) {
    int i = blockIdx.x * blockDim.x + threadIdx.x;   // over N*128
    int c = i >> 7;
    xz[i] = cnt[c] * xdiff[i];
}

__global__ void scale_z2(const float* __restrict__ Y1,
                         const float* __restrict__ cnt,
                         float* __restrict__ z2) {
    int i = blockIdx.x * blockDim.x + threadIdx.x;   // over N*256
    int c = i >> 8;
    int f = i & 255;
    int k1 = f >> 7;
    int d = f & 127;
    z2[i] = cnt[c] * Y1[((size_t)(k1 * NN + c)) * DD + d];
}

// C[M,N] = A[M,Kd] @ B[Kd,N]; if X != nullptr: C = X - tau[0] * (A@B)
// BM=BN=64, BK=16, 256 threads, 4x4 per thread.
__global__ __launch_bounds__(256)
void sgemm64(const float* __restrict__ A, const float* __restrict__ B,
             float* __restrict__ C, int M, int N, int Kd,
             const float* __restrict__ X, const float* __restrict__ tau) {
    __shared__ float As[16][64];   // As[k][m]
    __shared__ float Bs[16][64];   // Bs[k][n]

    const int tid = threadIdx.x;
    const int tx = tid & 15;       // col group (x4)
    const int ty = tid >> 4;       // row group (x4)
    const int row0 = blockIdx.y * 64;
    const int col0 = blockIdx.x * 64;

    // A-tile load mapping: 64 rows x 16 k, one float4 per thread
    const int am = tid >> 2;           // 0..63
    const int ak = (tid & 3) * 4;      // 0,4,8,12
    // B-tile load mapping: 16 k x 64 n, one float4 per thread
    const int bk = tid >> 4;           // 0..15
    const int bn = (tid & 15) * 4;     // 0..60

    const float* Abase = A + (size_t)(row0 + am) * Kd + ak;

    float acc[4][4] = {};

    for (int k0 = 0; k0 < Kd; k0 += 16) {
        float4 av = *(const float4*)(Abase + k0);
        float4 bv = *(const float4*)(B + (size_t)(k0 + bk) * N + col0 + bn);
        As[ak + 0][am] = av.x;
        As[ak + 1][am] = av.y;
        As[ak + 2][am] = av.z;
        As[ak + 3][am] = av.w;
        *(float4*)&Bs[bk][bn] = bv;
        __syncthreads();

#pragma unroll
        for (int k = 0; k < 16; ++k) {
            const float4 a = *(const float4*)&As[k][ty * 4];
            const float4 b = *(const float4*)&Bs[k][tx * 4];
            float a4[4] = {a.x, a.y, a.z, a.w};
            float b4[4] = {b.x, b.y, b.z, b.w};
#pragma unroll
            for (int i = 0; i < 4; ++i)
#pragma unroll
                for (int j = 0; j < 4; ++j)
                    acc[i][j] += a4[i] * b4[j];
        }
        __syncthreads();
    }

    const float t = X ? tau[0] : 0.0f;
#pragma unroll
    for (int i = 0; i < 4; ++i) {
        size_t off = (size_t)(row0 + ty * 4 + i) * N + col0 + tx * 4;
        float4 r = make_float4(acc[i][0], acc[i][1], acc[i][2], acc[i][3]);
        if (X) {
            float4 xv = *(const float4*)(X + off);
            r.x = xv.x - t * r.x;
            r.y = xv.y - t * r.y;
            r.z = xv.z - t * r.z;
            r.w = xv.w - t * r.w;
        }
        *(float4*)(C + off) = r;
    }
}

// E[r,e] = tanh(feat(r) . W[:,e] + b[e]); block = (64, 4): 4 rows, 64 emb cols
__global__ __launch_bounds__(256)
void encoder_k(const float* __restrict__ xdiff, const float* __restrict__ Y1,
               const float* __restrict__ Y2, const float* __restrict__ W,
               const float* __restrict__ bvec, float* __restrict__ E) {
    __shared__ float feat[4][INDIM];
    const int e = threadIdx.x;   // 0..63
    const int yr = threadIdx.y;  // 0..3
    const int r = blockIdx.x * 4 + yr;

    for (int i = e; i < INDIM; i += 64) {
        float v;
        if (i < 128) {
            v = xdiff[(size_t)r * DD + i];
        } else if (i < 384) {
            int f = i - 128;
            int k1 = f >> 7, d = f & 127;
            v = Y1[((size_t)(k1 * NN + r)) * DD + d];
        } else {
            int f = i - 384;
            int k2 = f >> 8, d2 = f & 255;
            v = Y2[((size_t)(k2 * NN + r)) * 256 + d2];
        }
        feat[yr][i] = v;
    }
    __syncthreads();

    float acc = bvec[e];
#pragma unroll 8
    for (int f = 0; f < INDIM; ++f)
        acc += feat[yr][f] * W[f * EMB + e];
    E[(size_t)r * EMB + e] = tanhf(acc);
}

__global__ void gather_k(const float* __restrict__ E,
                         const int* __restrict__ n_id,
                         float* __restrict__ out) {
    int i = blockIdx.x * blockDim.x + threadIdx.x;   // over N*64
    int j = i >> 6;
    int e = i & 63;
    out[i] = E[(size_t)n_id[j] * EMB + e];
}

extern "C" void kernel_launch(void* const* d_in, const int* in_sizes, int n_in,
                              void* d_out, int out_size, void* d_ws, size_t ws_size,
                              hipStream_t stream) {
    const float* x    = (const float*)d_in[0];   // [8192,128]
    const float* K    = (const float*)d_in[1];   // [2,8192,8192]
    const float* L    = (const float*)d_in[2];   // [8192,8192]
    const float* tau  = (const float*)d_in[3];   // [1]
    const float* W    = (const float*)d_in[4];   // [896,64]
    const float* b    = (const float*)d_in[5];   // [64]
    const int*   n_id = (const int*)d_in[6];     // [8192]
    float* out = (float*)d_out;                  // [8192,64]

    float* ws    = (float*)d_ws;
    float* xdiff = ws;                   // 1048576
    float* cnt   = xdiff + 1048576;      // 8192
    float* xz    = cnt + 8192;           // 1048576
    float* Y1    = xz + 1048576;         // 2097152
    float* z2    = Y1 + 2097152;         // 2097152
    float* Y2    = z2 + 2097152;         // 4194304
    float* E     = Y2 + 4194304;         // 524288  (total ~44 MB)

    zero_f<<<32, 256, 0, stream>>>(cnt, NN);
    hist_k<<<32, 256, 0, stream>>>(n_id, cnt);

    // xdiff = x - tau * L @ x          (M=8192, N=128, K=8192)
    sgemm64<<<dim3(2, 128), 256, 0, stream>>>(L, x, xdiff, NN, DD, NN, x, tau);

    scale_xz<<<4096, 256, 0, stream>>>(xdiff, cnt, xz);

    // Y1 = [K0;K1] @ xz               (M=16384, N=128, K=8192)
    sgemm64<<<dim3(2, 256), 256, 0, stream>>>(K, xz, Y1, 2 * NN, DD, NN, nullptr, nullptr);

    scale_z2<<<8192, 256, 0, stream>>>(Y1, cnt, z2);

    // Y2 = [K0;K1] @ z2               (M=16384, N=256, K=8192)
    sgemm64<<<dim3(4, 256), 256, 0, stream>>>(K, z2, Y2, 2 * NN, 256, NN, nullptr, nullptr);

    encoder_k<<<2048, dim3(64, 4), 0, stream>>>(xdiff, Y1, Y2, W, b, E);
    gather_k<<<2048, 256, 0, stream>>>(E, n_id, out);
}

// Round 2
// 1233.189 us; speedup vs baseline: 2.4292x; 2.4292x over previous
//
#include <hip/hip_runtime.h>

#define NN 8192
#define DD 128
#define EMB 64
#define INDIM 896
#define KD 8192

using half8  = __attribute__((ext_vector_type(8))) _Float16;
using floatx4 = __attribute__((ext_vector_type(4))) float;

__device__ inline void glds16(const void* g, void* l) {
    __builtin_amdgcn_global_load_lds(
        (const __attribute__((address_space(1))) unsigned int*)g,
        (__attribute__((address_space(3))) unsigned int*)l, 16, 0, 0);
}

// ---------------------------------------------------------------------------
// Algebra (cnt[c] = #{i : n_id[i]==c}):
//   S = L@x ; xdiff = x - tau*S ; xzT[d][c] = cnt[c]*xdiff[c,d]  (fp16, [128][8192])
//   Y1 = K@xz (M=16384) ; z2T[k1*128+d][c] = cnt[c]*Y1[k1][c][d] (fp16 [256][8192])
//   Y2 = K@z2 (M=16384, N=256)
//   E[r] = tanh(feat(r).W + b), out[j] = E[n_id[j]]
// ---------------------------------------------------------------------------

__global__ void hist_k(const int* __restrict__ n_id, float* __restrict__ cnt) {
    int i = blockIdx.x * blockDim.x + threadIdx.x;
    if (i < NN) atomicAdd(&cnt[n_id[i]], 1.0f);
}

// dst fp16 [Cd][R] = (cnt ? cnt[r] : 1) * src fp32 [R][Cd], transposed
__global__ __launch_bounds__(256)
void transpose_cvt(const float* __restrict__ src, const float* __restrict__ cnt,
                   _Float16* __restrict__ dst, int R, int Cd) {
    __shared__ float tile[64][65];
    const int r0 = blockIdx.y * 64, c0 = blockIdx.x * 64;
    const int t = threadIdx.x;
    const int c4 = (t & 15) * 4;
    const int rb = t >> 4;
#pragma unroll
    for (int i = 0; i < 4; ++i) {
        int r = rb + i * 16;
        float4 v = *(const float4*)&src[(size_t)(r0 + r) * Cd + c0 + c4];
        float s = cnt ? cnt[r0 + r] : 1.0f;
        tile[r][c4 + 0] = v.x * s;
        tile[r][c4 + 1] = v.y * s;
        tile[r][c4 + 2] = v.z * s;
        tile[r][c4 + 3] = v.w * s;
    }
    __syncthreads();
#pragma unroll
    for (int p = 0; p < 2; ++p) {
        int f = t + p * 256;
        int cc = f >> 3, rseg = f & 7;
        half8 h;
#pragma unroll
        for (int j = 0; j < 8; ++j) h[j] = (_Float16)tile[rseg * 8 + j][cc];
        *(half8*)&dst[(size_t)(c0 + cc) * R + r0 + rseg * 8] = h;
    }
}

__global__ void fuse_xdiff(const float* __restrict__ x, const float* __restrict__ S,
                           const float* __restrict__ tau, float* __restrict__ xdiff) {
    int i = blockIdx.x * blockDim.x + threadIdx.x;   // over N*128
    xdiff[i] = x[i] - tau[0] * S[i];
}

// C[M][ldc] (+)= A[M][KD] @ BT[ldc-cols][KD]^T   (A fp32->fp16 in staging, BT fp16)
// BM=128, BN=128, BK=32, 256 threads, 4 waves 2x2, 4x4 MFMA tiles per wave.
template<bool ATOMIC>
__global__ __launch_bounds__(256)
void mfma_gemm(const float* __restrict__ A, const _Float16* __restrict__ BT,
               float* __restrict__ C, int ldc, int Kslab) {
    __shared__ _Float16 As[128 * 40];   // row-major [row][k], pad 32->40 halfs
    __shared__ _Float16 Bs[128 * 32];   // [n][k], NO pad (global_load_lds layout)

    const int tid  = threadIdx.x;
    const int lane = tid & 63;
    const int w    = tid >> 6;
    const int wr   = w >> 1, wc = w & 1;
    const int l15  = lane & 15, q = lane >> 4;
    const long row0 = (long)blockIdx.y * 128;
    const int  col0 = blockIdx.x * 128;
    const int  kbeg = blockIdx.z * Kslab;

    // A staging: seg f = tid (rows 0..63 handled via f>>2? f covers r=f>>2), plus f+256
    const int r_a = tid >> 2;              // 0..63
    const int ks  = (tid & 3) * 8;         // 0,8,16,24
    const float* Ag0 = A + (row0 + r_a) * (long)KD + ks;
    const float* Ag1 = Ag0 + 64L * KD;
    _Float16* As0 = &As[r_a * 40 + ks];
    _Float16* As1 = &As[(r_a + 64) * 40 + ks];

    // B staging: wave w stages 16-row chunks 2w, 2w+1 via global_load_lds
    const int ch0 = 2 * w;
    const _Float16* Bg0 = BT + (long)(col0 + ch0 * 16 + (lane >> 2)) * KD + (lane & 3) * 8;
    const _Float16* Bg1 = Bg0 + 16L * KD;
    _Float16* Bl0 = &Bs[ch0 * 512 + lane * 8];
    _Float16* Bl1 = Bl0 + 512;

    floatx4 acc[4][4] = {};

    for (int kk = 0; kk < Kslab; kk += 32) {
        const int k0 = kbeg + kk;
        glds16(Bg0 + k0, Bl0);
        glds16(Bg1 + k0, Bl1);

        float4 a0 = *(const float4*)(Ag0 + k0);
        float4 a1 = *(const float4*)(Ag0 + k0 + 4);
        float4 c0v = *(const float4*)(Ag1 + k0);
        float4 c1v = *(const float4*)(Ag1 + k0 + 4);
        half8 h0, h1;
        h0[0] = (_Float16)a0.x; h0[1] = (_Float16)a0.y; h0[2] = (_Float16)a0.z; h0[3] = (_Float16)a0.w;
        h0[4] = (_Float16)a1.x; h0[5] = (_Float16)a1.y; h0[6] = (_Float16)a1.z; h0[7] = (_Float16)a1.w;
        h1[0] = (_Float16)c0v.x; h1[1] = (_Float16)c0v.y; h1[2] = (_Float16)c0v.z; h1[3] = (_Float16)c0v.w;
        h1[4] = (_Float16)c1v.x; h1[5] = (_Float16)c1v.y; h1[6] = (_Float16)c1v.z; h1[7] = (_Float16)c1v.w;
        *(half8*)As0 = h0;
        *(half8*)As1 = h1;

        __syncthreads();

        half8 af[4], bf[4];
#pragma unroll
        for (int mt = 0; mt < 4; ++mt)
            af[mt] = *(const half8*)&As[(wr * 64 + mt * 16 + l15) * 40 + q * 8];
#pragma unroll
        for (int nt = 0; nt < 4; ++nt)
            bf[nt] = *(const half8*)&Bs[(wc * 64 + nt * 16 + l15) * 32 + q * 8];
#pragma unroll
        for (int mt = 0; mt < 4; ++mt)
#pragma unroll
            for (int nt = 0; nt < 4; ++nt)
                acc[mt][nt] = __builtin_amdgcn_mfma_f32_16x16x32_f16(af[mt], bf[nt], acc[mt][nt], 0, 0, 0);

        __syncthreads();
    }

#pragma unroll
    for (int mt = 0; mt < 4; ++mt)
#pragma unroll
        for (int nt = 0; nt < 4; ++nt)
#pragma unroll
            for (int r = 0; r < 4; ++r) {
                long row = row0 + wr * 64 + mt * 16 + q * 4 + r;
                int  col = col0 + wc * 64 + nt * 16 + l15;
                if (ATOMIC) atomicAdd(&C[row * ldc + col], acc[mt][nt][r]);
                else        C[row * ldc + col] = acc[mt][nt][r];
            }
}

__global__ __launch_bounds__(256)
void encoder_k(const float* __restrict__ xdiff, const float* __restrict__ Y1,
               const float* __restrict__ Y2, const float* __restrict__ W,
               const float* __restrict__ bvec, float* __restrict__ E) {
    __shared__ float feat[4][INDIM];
    const int e = threadIdx.x;
    const int yr = threadIdx.y;
    const int r = blockIdx.x * 4 + yr;

    for (int i = e; i < INDIM; i += 64) {
        float v;
        if (i < 128) {
            v = xdiff[(size_t)r * DD + i];
        } else if (i < 384) {
            int f = i - 128;
            int k1 = f >> 7, d = f & 127;
            v = Y1[((size_t)(k1 * NN + r)) * DD + d];
        } else {
            int f = i - 384;
            int k2 = f >> 8, d2 = f & 255;
            v = Y2[((size_t)(k2 * NN + r)) * 256 + d2];
        }
        feat[yr][i] = v;
    }
    __syncthreads();

    float acc = bvec[e];
#pragma unroll 8
    for (int f = 0; f < INDIM; ++f)
        acc += feat[yr][f] * W[f * EMB + e];
    E[(size_t)r * EMB + e] = tanhf(acc);
}

__global__ void gather_k(const float* __restrict__ E,
                         const int* __restrict__ n_id,
                         float* __restrict__ out) {
    int i = blockIdx.x * blockDim.x + threadIdx.x;
    int j = i >> 6;
    int e = i & 63;
    out[i] = E[(size_t)n_id[j] * EMB + e];
}

extern "C" void kernel_launch(void* const* d_in, const int* in_sizes, int n_in,
                              void* d_out, int out_size, void* d_ws, size_t ws_size,
                              hipStream_t stream) {
    const float* x    = (const float*)d_in[0];
    const float* K    = (const float*)d_in[1];   // [2,8192,8192] -> [16384,8192]
    const float* L    = (const float*)d_in[2];
    const float* tau  = (const float*)d_in[3];
    const float* W    = (const float*)d_in[4];
    const float* b    = (const float*)d_in[5];
    const int*   n_id = (const int*)d_in[6];
    float* out = (float*)d_out;

    // workspace carve-up (floats / halfs)
    float* ws = (float*)d_ws;
    float* cnt   = ws;                       // 8192 f
    float* S     = cnt + NN;                 // 1M f
    float* xdiff = S + NN * DD;              // 1M f
    float* Y1    = xdiff + NN * DD;          // 2M f
    float* Y2    = Y1 + 2 * NN * DD;         // 4M f
    float* E     = Y2 + 2 * NN * 256;        // 512K f
    _Float16* BT1 = (_Float16*)(E + NN * EMB);   // 1M h  (x^T)
    _Float16* xzT = BT1 + NN * DD;               // 1M h
    _Float16* z2T = xzT + NN * DD;               // 2M h

    hipMemsetAsync(cnt, 0, NN * sizeof(float), stream);
    hipMemsetAsync(S, 0, NN * DD * sizeof(float), stream);
    hipMemsetAsync(Y1, 0, 2 * NN * DD * sizeof(float), stream);
    hipMemsetAsync(Y2, 0, 2 * NN * 256 * sizeof(float), stream);

    hist_k<<<32, 256, 0, stream>>>(n_id, cnt);

    // BT1 = x^T (fp16)
    transpose_cvt<<<dim3(2, 128), 256, 0, stream>>>(x, nullptr, BT1, NN, DD);

    // S = L @ x   (M=8192, N=128, SK=8 -> 512 blocks)
    mfma_gemm<true><<<dim3(1, 64, 8), 256, 0, stream>>>(L, BT1, S, DD, KD / 8);

    fuse_xdiff<<<NN * DD / 256, 256, 0, stream>>>(x, S, tau, xdiff);

    // xzT = (cnt * xdiff)^T fp16
    transpose_cvt<<<dim3(2, 128), 256, 0, stream>>>(xdiff, cnt, xzT, NN, DD);

    // Y1 = K @ xz  (M=16384, N=128, SK=4 -> 512 blocks)
    mfma_gemm<true><<<dim3(1, 128, 4), 256, 0, stream>>>(K, xzT, Y1, DD, KD / 4);

    // z2T[k1*128+d][c] = cnt[c]*Y1[k1][c][d]
    transpose_cvt<<<dim3(2, 128), 256, 0, stream>>>(Y1, cnt, z2T, NN, DD);
    transpose_cvt<<<dim3(2, 128), 256, 0, stream>>>(Y1 + (size_t)NN * DD, cnt,
                                                    z2T + (size_t)DD * NN, NN, DD);

    // Y2 = K @ z2  (M=16384, N=256, SK=2 -> 512 blocks)
    mfma_gemm<true><<<dim3(2, 128, 2), 256, 0, stream>>>(K, z2T, Y2, 256, KD / 2);

    encoder_k<<<NN / 4, dim3(64, 4), 0, stream>>>(xdiff, Y1, Y2, W, b, E);
    gather_k<<<NN * EMB / 256, 256, 0, stream>>>(E, n_id, out);
}